// Round 14
// baseline (263.957 us; speedup 1.0000x reference)
//
#include <hip/hip_runtime.h>
#include <math.h>

// z[i] = R @ x[i], R from ZYX-intrinsic Euler angles in weight[3].
// x/out: [N,3] f32 row-major. N = 8,000,000 -> 6M float4 = 2M groups (3 f4 = 4 pts).
//
// Round 14 (= round-13 resubmit after broker timeout) — measurement round.
// Main: round-3 structure (plain stores; nt stores caused 1.5x write
// amplification via partial-line writeback, r12; explicit pipeline collapsed
// by compiler, VGPR=32, r12). Probe: coalesced f4 copy x->ws repeated 3x with
// asm memory barriers (anti-CSE) so its dispatch (~100-240us) tops the
// profile table. Probe BW answers: is the 2.45 TB/s wall environmental or
// kernel-structural?

typedef float f4 __attribute__((ext_vector_type(4)));

#define BLOCK 256
#define GRID 2048

__global__ __launch_bounds__(BLOCK) void rot_apply_kernel(
    const float* __restrict__ x,
    const float* __restrict__ w,
    float* __restrict__ out,
    long long n_groups)
{
    const f4* __restrict__ x4 = (const f4*)x;
    f4* __restrict__ o4 = (f4*)out;

    // R: uniform across all lanes (same inputs -> no divergence), hides under loads
    float ea = w[0], eb = w[1], ec = w[2];
    float sa, ca, sb, cb, sc, cc;
    sincosf(ea, &sa, &ca);
    sincosf(eb, &sb, &cb);
    sincosf(ec, &sc, &cc);
    const float R00 = cc * cb, R01 = sa * sb * cc - ca * sc, R02 = ca * sb * cc + sa * sc;
    const float R10 = cb * sc, R11 = sa * sb * sc + ca * cc, R12 = ca * sb * sc - sa * cc;
    const float R20 = -sb,     R21 = sa * cb,                R22 = ca * cb;

    const long long stride = (long long)gridDim.x * blockDim.x;
    for (long long g = (long long)blockIdx.x * blockDim.x + threadIdx.x;
         g < n_groups; g += stride) {
        const long long b = 3ll * g;
        f4 v0 = x4[b];
        f4 v1 = x4[b + 1];
        f4 v2 = x4[b + 2];

        float px0 = v0.x, py0 = v0.y, pz0 = v0.z;
        float px1 = v0.w, py1 = v1.x, pz1 = v1.y;
        float px2 = v1.z, py2 = v1.w, pz2 = v2.x;
        float px3 = v2.y, py3 = v2.z, pz3 = v2.w;

        f4 w0, w1, w2;
        w0.x = fmaf(R00, px0, fmaf(R01, py0, R02 * pz0)); // a0
        w0.y = fmaf(R10, px0, fmaf(R11, py0, R12 * pz0)); // b0
        w0.z = fmaf(R20, px0, fmaf(R21, py0, R22 * pz0)); // c0
        w0.w = fmaf(R00, px1, fmaf(R01, py1, R02 * pz1)); // a1
        w1.x = fmaf(R10, px1, fmaf(R11, py1, R12 * pz1)); // b1
        w1.y = fmaf(R20, px1, fmaf(R21, py1, R22 * pz1)); // c1
        w1.z = fmaf(R00, px2, fmaf(R01, py2, R02 * pz2)); // a2
        w1.w = fmaf(R10, px2, fmaf(R11, py2, R12 * pz2)); // b2
        w2.x = fmaf(R20, px2, fmaf(R21, py2, R22 * pz2)); // c2
        w2.y = fmaf(R00, px3, fmaf(R01, py3, R02 * pz3)); // a3
        w2.z = fmaf(R10, px3, fmaf(R11, py3, R12 * pz3)); // b3
        w2.w = fmaf(R20, px3, fmaf(R21, py3, R22 * pz3)); // c3

        o4[b]     = w0;
        o4[b + 1] = w1;
        o4[b + 2] = w2;
    }
}

// Streaming-copy probe: lane-contiguous f4 copy x -> ws, repeated 3x (asm
// memory barriers prevent rep elimination). Its rocprof row (dur_us,
// hbm_gbps) measures this environment's in-kernel 2-stream ceiling.
__global__ __launch_bounds__(BLOCK) void copy_probe_kernel(
    const float* __restrict__ x,
    float* __restrict__ ws,
    long long n4)
{
    const f4* __restrict__ x4 = (const f4*)x;
    f4* __restrict__ w4 = (f4*)ws;
    const long long stride = (long long)gridDim.x * blockDim.x;
    const long long i0 = (long long)blockIdx.x * blockDim.x + threadIdx.x;
#pragma unroll 1
    for (int rep = 0; rep < 3; ++rep) {
        for (long long i = i0; i < n4; i += stride) {
            w4[i] = x4[i];
        }
        asm volatile("" ::: "memory");   // force re-execution of each pass
    }
}

extern "C" void kernel_launch(void* const* d_in, const int* in_sizes, int n_in,
                              void* d_out, int out_size, void* d_ws, size_t ws_size,
                              hipStream_t stream) {
    const float* x = (const float*)d_in[0];
    const float* w = (const float*)d_in[1];
    float* out = (float*)d_out;

    const long long n_floats = (long long)in_sizes[0];   // 24,000,000
    const long long n_groups = n_floats / 12;            // 2,000,000 (exact)
    const long long n4 = n_floats / 4;                   // 6,000,000

    const int block = BLOCK;
    int grid = GRID;
    long long needed = (n_groups + block - 1) / block;
    if (needed < grid) grid = (int)needed;

    rot_apply_kernel<<<grid, block, 0, stream>>>(x, w, out, n_groups);

    // probe sized to workspace (expected ws ~288 MB >= 96 MB needed)
    long long probe_n4 = (long long)(ws_size / sizeof(f4));
    if (probe_n4 > n4) probe_n4 = n4;
    if (probe_n4 > 0) {
        copy_probe_kernel<<<GRID, BLOCK, 0, stream>>>(x, (float*)d_ws, probe_n4);
    }
}